// Round 2
// baseline (383.358 us; speedup 1.0000x reference)
//
#include <hip/hip_runtime.h>
#include <hip/hip_bf16.h>

// Problem constants (fixed by setup_inputs)
#define B_  32
#define L_  1024
#define C_  2
#define M_  96
#define E_  1024
#define K_  192           // sin(96) ++ cos(96)
#define NROWS (B_*C_*L_)  // 65536 global rows, ordered (b, c, l)

typedef __attribute__((ext_vector_type(8))) short short8;
typedef __attribute__((ext_vector_type(4))) float f32x4;

static __device__ __forceinline__ unsigned short f2bf(float f) {
    unsigned u = __float_as_uint(f);
    u += 0x7fff + ((u >> 16) & 1);   // RNE
    return (unsigned short)(u >> 16);
}

// ---------------------------------------------------------------------------
// Kernel 1: pack the 4 tables [C,M,E] f32 into MFMA-B-fragment order, bf16.
// Layout: pT[tab2(2: alpha,beta)][c(2)][ks(6)][kc(4)][e(1024)][j(8)] ushort
// k = ks*32 + kc*8 + j;  k<96 -> *_sin[k], else *_cos[k-96]
// ---------------------------------------------------------------------------
__global__ void pack_tables(const float* __restrict__ as, const float* __restrict__ ac,
                            const float* __restrict__ bs, const float* __restrict__ bc,
                            unsigned short* __restrict__ pT) {
    int tid = blockIdx.x * blockDim.x + threadIdx.x;       // 98304 threads
    if (tid >= 2*2*6*4*1024) return;
    int e    = tid & 1023;
    int kc   = (tid >> 10) & 3;
    int rest = tid >> 12;          // 0..23
    int ks   = rest % 6;
    int t2c  = rest / 6;           // 0..3
    int tab2 = t2c >> 1, ch = t2c & 1;
    const float* ssrc = tab2 ? bs : as;
    const float* csrc = tab2 ? bc : ac;
    short8 v;
#pragma unroll
    for (int j = 0; j < 8; ++j) {
        int k = ks*32 + kc*8 + j;
        float f = (k < M_) ? ssrc[((size_t)ch*M_ + k)*E_ + e]
                           : csrc[((size_t)ch*M_ + (k - M_))*E_ + e];
        v[j] = (short)f2bf(f);
    }
    *(short8*)&pT[(size_t)tid * 8] = v;
}

// ---------------------------------------------------------------------------
// Kernel 2: S[row][k] bf16, row = b*2048 + c*1024 + l; k<96 sin, k>=96 cos
// ---------------------------------------------------------------------------
__global__ void sprep(const float* __restrict__ t, unsigned short* __restrict__ S) {
    int tid = blockIdx.x * blockDim.x + threadIdx.x;   // NROWS*24
    if (tid >= NROWS*24) return;
    int q   = tid % 24;
    int row = tid / 24;
    int b = row >> 11, ch = (row >> 10) & 1, l = row & 1023;
    float tv = t[((size_t)b*L_ + l)*C_ + ch];
    const float w = 6.2831853071795864769f / 1000.0f;
    float wt = w * tv;
    ushort4 sv, cv;
#pragma unroll
    for (int j = 0; j < 4; ++j) {
        int m = q*4 + j;
        float s, c;
        sincosf(wt * (float)m, &s, &c);
        ((unsigned short*)&sv)[j] = f2bf(s);
        ((unsigned short*)&cv)[j] = f2bf(c);
    }
    *(ushort4*)&S[(size_t)row*K_ + q*4]       = sv;
    *(ushort4*)&S[(size_t)row*K_ + M_ + q*4]  = cv;
}

// ---------------------------------------------------------------------------
// Kernel 3: per-batch stable ascending bitonic sort of 2048 (t, idx) pairs.
// Writes out_t, out_m directly, and inverse permutation inv[b*2048+src]=dst.
// Keys: t >= 0 so float bits sort as unsigned; index in low bits => stable.
// ---------------------------------------------------------------------------
__global__ __launch_bounds__(1024) void sort_kernel(
        const float* __restrict__ t, const float* __restrict__ mask,
        float* __restrict__ out_t, float* __restrict__ out_m,
        int* __restrict__ inv) {
    __shared__ unsigned long long sk[2048];
    int b = blockIdx.x, tid = threadIdx.x;
    for (int i = tid; i < 2048; i += 1024) {
        int ch = i >> 10, l = i & 1023;
        float tv = t[((size_t)b*L_ + l)*C_ + ch];
        sk[i] = ((unsigned long long)__float_as_uint(tv) << 32) | (unsigned)i;
    }
    __syncthreads();
    for (int k = 2; k <= 2048; k <<= 1) {
        for (int j = k >> 1; j > 0; j >>= 1) {
            int i = ((tid & ~(j - 1)) << 1) | (tid & (j - 1));
            int p = i | j;
            bool up = ((i & k) == 0);
            unsigned long long a = sk[i], c = sk[p];
            if ((a > c) == up) { sk[i] = c; sk[p] = a; }
            __syncthreads();
        }
    }
    for (int i = tid; i < 2048; i += 1024) {
        unsigned long long key = sk[i];
        unsigned src = (unsigned)(key & 0xffffffffu);
        out_t[(size_t)b*2048 + i] = __uint_as_float((unsigned)(key >> 32));
        int ch = (int)(src >> 10), l = (int)(src & 1023);
        out_m[(size_t)b*2048 + i] = mask[((size_t)b*L_ + l)*C_ + ch];
        inv[b*2048 + (int)src] = i;
    }
}

// ---------------------------------------------------------------------------
// Kernel 4: main MFMA modulate + scatter.
// Block: 256 thr (4 waves). Tile: 64 rows x 256 cols. Wave w: cols [w*64, w*64+64).
// grid = (NROWS/64, E/256). K-loop: 6 steps of 32 (bf16 16x16x32 MFMA).
// Dual accumulators: alpha and beta GEMMs share the A (S) operand.
// ---------------------------------------------------------------------------
__global__ __launch_bounds__(256) void main_kernel(
        const unsigned short* __restrict__ S, const unsigned short* __restrict__ pT,
        const int* __restrict__ inv, const float* __restrict__ x,
        const float* __restrict__ W, const float* __restrict__ bemb,
        float* __restrict__ out_x) {
    int lane = threadIdx.x & 63;
    int wave = threadIdx.x >> 6;
    int lr = lane & 15, lk = lane >> 4;
    int rowbase = blockIdx.x * 64;
    int b  = rowbase >> 11;
    int ch = (rowbase >> 10) & 1;
    int n0 = blockIdx.y * 256 + wave * 64;

    const unsigned short* pA = pT + (size_t)ch       * (6*4*1024*8); // alpha tables
    const unsigned short* pB = pT + (size_t)(2 + ch) * (6*4*1024*8); // beta tables

    f32x4 accA[4][4] = {};
    f32x4 accB[4][4] = {};

#pragma unroll
    for (int ks = 0; ks < 6; ++ks) {
        short8 a[4];
#pragma unroll
        for (int rt = 0; rt < 4; ++rt) {
            int row = rowbase + rt*16 + lr;
            a[rt] = *(const short8*)&S[(size_t)row*K_ + ks*32 + lk*8];
        }
#pragma unroll
        for (int nt = 0; nt < 4; ++nt) {
            int n = n0 + nt*16 + lr;
            size_t off = (((size_t)ks*4 + lk)*1024 + n)*8;
            short8 bA = *(const short8*)&pA[off];
            short8 bB = *(const short8*)&pB[off];
#pragma unroll
            for (int rt = 0; rt < 4; ++rt) {
                accA[rt][nt] = __builtin_amdgcn_mfma_f32_16x16x32_bf16(a[rt], bA, accA[rt][nt], 0, 0, 0);
                accB[rt][nt] = __builtin_amdgcn_mfma_f32_16x16x32_bf16(a[rt], bB, accB[rt][nt], 0, 0, 0);
            }
        }
    }

    // Epilogue: mod = (x*W + b) * alpha + beta, scatter rows by inv perm.
    float wv[4], bv[4];
#pragma unroll
    for (int nt = 0; nt < 4; ++nt) {
        int e = n0 + nt*16 + lr;
        wv[nt] = W[e];
        bv[nt] = bemb[e];
    }
    int l_base = rowbase & 1023;
#pragma unroll
    for (int rt = 0; rt < 4; ++rt) {
#pragma unroll
        for (int r = 0; r < 4; ++r) {
            int l = l_base + rt*16 + lk*4 + r;           // D row = (lane>>4)*4 + reg
            float xv = x[((size_t)b*L_ + l)*C_ + ch];
            int dst = inv[(b*C_ + ch)*L_ + l];
            float* orow = out_x + ((size_t)b*2048 + dst)*E_;
#pragma unroll
            for (int nt = 0; nt < 4; ++nt) {
                float emb = xv*wv[nt] + bv[nt];
                orow[n0 + nt*16 + lr] = emb*accA[rt][nt][r] + accB[rt][nt][r];
            }
        }
    }
}

// ---------------------------------------------------------------------------
extern "C" void kernel_launch(void* const* d_in, const int* in_sizes, int n_in,
                              void* d_out, int out_size, void* d_ws, size_t ws_size,
                              hipStream_t stream) {
    const float* x    = (const float*)d_in[0];
    const float* t    = (const float*)d_in[1];
    const float* mask = (const float*)d_in[2];
    const float* W    = (const float*)d_in[3];
    const float* bemb = (const float*)d_in[4];
    const float* as_  = (const float*)d_in[5];
    const float* ac_  = (const float*)d_in[6];
    const float* bs_  = (const float*)d_in[7];
    const float* bc_  = (const float*)d_in[8];

    float* out_x = (float*)d_out;                        // [B, 2048, 1024]
    float* out_t = out_x + (size_t)B_*2048*E_;           // [B, 2048]
    float* out_m = out_t + (size_t)B_*2048;              // [B, 2048]

    // workspace layout
    char* ws = (char*)d_ws;
    int*            inv = (int*)ws;                               // 256 KB
    unsigned short* pT  = (unsigned short*)(ws + 262144);         // 1.5 MB
    unsigned short* S   = (unsigned short*)(ws + 262144 + 1572864); // 25.2 MB

    pack_tables<<<dim3(384), dim3(256), 0, stream>>>(as_, ac_, bs_, bc_, pT);
    sprep<<<dim3((NROWS*24)/256), dim3(256), 0, stream>>>(t, S);
    sort_kernel<<<dim3(B_), dim3(1024), 0, stream>>>(t, mask, out_t, out_m, inv);
    main_kernel<<<dim3(NROWS/64, E_/256), dim3(256), 0, stream>>>(S, pT, inv, x, W, bemb, out_x);
}

// Round 3
// 375.905 us; speedup vs baseline: 1.0198x; 1.0198x over previous
//
#include <hip/hip_runtime.h>
#include <hip/hip_bf16.h>

// Problem constants (fixed by setup_inputs)
#define B_  32
#define L_  1024
#define C_  2
#define M_  96
#define E_  1024
#define K_  192           // sin(96) ++ cos(96)
#define NROWS (B_*C_*L_)  // 65536 global rows, ordered (b, c, l)

typedef __attribute__((ext_vector_type(8))) short short8;
typedef __attribute__((ext_vector_type(4))) float f32x4;

static __device__ __forceinline__ unsigned short f2bf(float f) {
    unsigned u = __float_as_uint(f);
    u += 0x7fff + ((u >> 16) & 1);   // RNE
    return (unsigned short)(u >> 16);
}

// ---------------------------------------------------------------------------
// Kernel 1: pack the 4 tables [C,M,E] f32 into MFMA-B-fragment order, bf16.
// Layout: pT[tab2(2: alpha,beta)][c(2)][ks(6)][kc(4)][e(1024)][j(8)] ushort
// k = ks*32 + kc*8 + j;  k<96 -> *_sin[k], else *_cos[k-96]
// ---------------------------------------------------------------------------
__global__ void pack_tables(const float* __restrict__ as, const float* __restrict__ ac,
                            const float* __restrict__ bs, const float* __restrict__ bc,
                            unsigned short* __restrict__ pT) {
    int tid = blockIdx.x * blockDim.x + threadIdx.x;       // 98304 threads
    if (tid >= 2*2*6*4*1024) return;
    int e    = tid & 1023;
    int kc   = (tid >> 10) & 3;
    int rest = tid >> 12;          // 0..23
    int ks   = rest % 6;
    int t2c  = rest / 6;           // 0..3
    int tab2 = t2c >> 1, ch = t2c & 1;
    const float* ssrc = tab2 ? bs : as;
    const float* csrc = tab2 ? bc : ac;
    short8 v;
#pragma unroll
    for (int j = 0; j < 8; ++j) {
        int k = ks*32 + kc*8 + j;
        float f = (k < M_) ? ssrc[((size_t)ch*M_ + k)*E_ + e]
                           : csrc[((size_t)ch*M_ + (k - M_))*E_ + e];
        v[j] = (short)f2bf(f);
    }
    *(short8*)&pT[(size_t)tid * 8] = v;
}

// ---------------------------------------------------------------------------
// Kernel 2: per-batch stable ascending bitonic sort of 2048 (t, idx) pairs.
// Writes out_t, out_m directly, and inverse permutation inv[b*2048+src]=dst.
// Keys: t >= 0 so float bits sort as unsigned; index in low bits => stable.
// ---------------------------------------------------------------------------
__global__ __launch_bounds__(1024) void sort_kernel(
        const float* __restrict__ t, const float* __restrict__ mask,
        float* __restrict__ out_t, float* __restrict__ out_m,
        int* __restrict__ inv) {
    __shared__ unsigned long long sk[2048];
    int b = blockIdx.x, tid = threadIdx.x;
    for (int i = tid; i < 2048; i += 1024) {
        int ch = i >> 10, l = i & 1023;
        float tv = t[((size_t)b*L_ + l)*C_ + ch];
        sk[i] = ((unsigned long long)__float_as_uint(tv) << 32) | (unsigned)i;
    }
    __syncthreads();
    for (int k = 2; k <= 2048; k <<= 1) {
        for (int j = k >> 1; j > 0; j >>= 1) {
            int i = ((tid & ~(j - 1)) << 1) | (tid & (j - 1));
            int p = i | j;
            bool up = ((i & k) == 0);
            unsigned long long a = sk[i], c = sk[p];
            if ((a > c) == up) { sk[i] = c; sk[p] = a; }
            __syncthreads();
        }
    }
    for (int i = tid; i < 2048; i += 1024) {
        unsigned long long key = sk[i];
        unsigned src = (unsigned)(key & 0xffffffffu);
        out_t[(size_t)b*2048 + i] = __uint_as_float((unsigned)(key >> 32));
        int ch = (int)(src >> 10), l = (int)(src & 1023);
        out_m[(size_t)b*2048 + i] = mask[((size_t)b*L_ + l)*C_ + ch];
        inv[b*2048 + (int)src] = i;
    }
}

// ---------------------------------------------------------------------------
// Kernel 3: fused main kernel.
// Block: 256 thr (4 waves). Tile: 64 rows x 1024 cols (4 column-quarters
// looped inside; wave w handles cols [cq*256 + w*64, +64)). grid = 1024.
// Phase 1: compute S (64 x 192 bf16) in LDS via sincos rotation recurrence
//          (row stride 200 shorts -> ds_read_b128 is 2-way aliased = free).
// Phase 2: per quarter, 6 k-steps of dual-accumulator 16x16x32 bf16 MFMA
//          (alpha/beta share the A operand), epilogue fuses emb=x*W+b and
//          scatters 64B row-segments to argsorted positions via inv (LDS).
// ---------------------------------------------------------------------------
__global__ __launch_bounds__(256) void main_kernel(
        const unsigned short* __restrict__ pT, const int* __restrict__ inv,
        const float* __restrict__ x, const float* __restrict__ t,
        const float* __restrict__ W, const float* __restrict__ bemb,
        float* __restrict__ out_x) {
    __shared__ unsigned short S_lds[64 * 200];   // 25.6 KB
    __shared__ float x_s[64];
    __shared__ int   inv_s[64];

    int tid  = threadIdx.x;
    int lane = tid & 63;
    int wave = tid >> 6;
    int lr = lane & 15, lk = lane >> 4;
    int rowbase = blockIdx.x * 64;
    int b  = rowbase >> 11;
    int ch = (rowbase >> 10) & 1;
    int l_base = rowbase & 1023;

    // ---- Phase 1: S tile into LDS, x/inv per-row caches ----
    {
        int row = tid >> 2;            // 0..63
        int q   = tid & 3;             // covers m in [q*24, q*24+24)
        int l   = l_base + row;
        float tv = t[((size_t)b*L_ + l)*C_ + ch];
        const float w = 6.2831853071795864769f / 1000.0f;
        float wt = w * tv;
        float s1, c1; sincosf(wt, &s1, &c1);
        float sm, cm; sincosf(wt * (float)(q*24), &sm, &cm);
        unsigned short* rowp = &S_lds[row * 200];
#pragma unroll
        for (int jj = 0; jj < 6; ++jj) {
            ushort4 sv, cv;
#pragma unroll
            for (int j = 0; j < 4; ++j) {
                ((unsigned short*)&sv)[j] = f2bf(sm);
                ((unsigned short*)&cv)[j] = f2bf(cm);
                float ns = sm*c1 + cm*s1;
                float nc = cm*c1 - sm*s1;
                sm = ns; cm = nc;
            }
            *(ushort4*)&rowp[q*24 + jj*4]      = sv;   // sin: k = m
            *(ushort4*)&rowp[96 + q*24 + jj*4] = cv;   // cos: k = 96+m
        }
        if (tid < 64) {
            int ll = l_base + tid;
            x_s[tid]   = x[((size_t)b*L_ + ll)*C_ + ch];
            inv_s[tid] = inv[(b*C_ + ch)*L_ + ll];
        }
    }
    __syncthreads();

    const unsigned short* pA = pT + (size_t)ch       * (6*4*1024*8); // alpha
    const unsigned short* pB = pT + (size_t)(2 + ch) * (6*4*1024*8); // beta

#pragma unroll 1
    for (int cq = 0; cq < 4; ++cq) {
        int n0 = cq*256 + wave*64;
        f32x4 accA[4][4] = {};
        f32x4 accB[4][4] = {};
#pragma unroll
        for (int ks = 0; ks < 6; ++ks) {
            short8 a[4];
#pragma unroll
            for (int rt = 0; rt < 4; ++rt) {
                int rl = rt*16 + lr;
                a[rt] = *(const short8*)&S_lds[rl*200 + ks*32 + lk*8];
            }
#pragma unroll
            for (int nt = 0; nt < 4; ++nt) {
                int n = n0 + nt*16 + lr;
                size_t off = (((size_t)ks*4 + lk)*1024 + n)*8;
                short8 bA = *(const short8*)&pA[off];
                short8 bB = *(const short8*)&pB[off];
#pragma unroll
                for (int rt = 0; rt < 4; ++rt) {
                    accA[rt][nt] = __builtin_amdgcn_mfma_f32_16x16x32_bf16(a[rt], bA, accA[rt][nt], 0, 0, 0);
                    accB[rt][nt] = __builtin_amdgcn_mfma_f32_16x16x32_bf16(a[rt], bB, accB[rt][nt], 0, 0, 0);
                }
            }
        }

        // Epilogue for this quarter: mod = (x*W + b)*alpha + beta, scattered.
        float wv[4], bv[4];
#pragma unroll
        for (int nt = 0; nt < 4; ++nt) {
            int e = n0 + nt*16 + lr;
            wv[nt] = W[e];
            bv[nt] = bemb[e];
        }
#pragma unroll
        for (int rt = 0; rt < 4; ++rt) {
#pragma unroll
            for (int r = 0; r < 4; ++r) {
                int row_l = rt*16 + lk*4 + r;          // D row = (lane>>4)*4 + reg
                float xv = x_s[row_l];
                int dst  = inv_s[row_l];
                float* orow = out_x + ((size_t)b*2048 + dst)*E_;
#pragma unroll
                for (int nt = 0; nt < 4; ++nt) {
                    float emb = xv*wv[nt] + bv[nt];
                    orow[n0 + nt*16 + lr] = emb*accA[rt][nt][r] + accB[rt][nt][r];
                }
            }
        }
    }
}

// ---------------------------------------------------------------------------
extern "C" void kernel_launch(void* const* d_in, const int* in_sizes, int n_in,
                              void* d_out, int out_size, void* d_ws, size_t ws_size,
                              hipStream_t stream) {
    const float* x    = (const float*)d_in[0];
    const float* t    = (const float*)d_in[1];
    const float* mask = (const float*)d_in[2];
    const float* W    = (const float*)d_in[3];
    const float* bemb = (const float*)d_in[4];
    const float* as_  = (const float*)d_in[5];
    const float* ac_  = (const float*)d_in[6];
    const float* bs_  = (const float*)d_in[7];
    const float* bc_  = (const float*)d_in[8];

    float* out_x = (float*)d_out;                        // [B, 2048, 1024]
    float* out_t = out_x + (size_t)B_*2048*E_;           // [B, 2048]
    float* out_m = out_t + (size_t)B_*2048;              // [B, 2048]

    // workspace layout
    char* ws = (char*)d_ws;
    int*            inv = (int*)ws;                       // 256 KB
    unsigned short* pT  = (unsigned short*)(ws + 262144); // 1.5 MB

    pack_tables<<<dim3(384), dim3(256), 0, stream>>>(as_, ac_, bs_, bc_, pT);
    sort_kernel<<<dim3(B_), dim3(1024), 0, stream>>>(t, mask, out_t, out_m, inv);
    main_kernel<<<dim3(NROWS/64), dim3(256), 0, stream>>>(pT, inv, x, t, W, bemb, out_x);
}